// Round 17
// baseline (350.339 us; speedup 1.0000x reference)
//
#include <hip/hip_runtime.h>

#define EMB 600
#define Q4  150   // EMB / 4
#define KP  608   // K padded (19 * 32)

typedef unsigned short ushortT;
typedef __attribute__((ext_vector_type(8))) short short8;
typedef __attribute__((ext_vector_type(4))) short short4v;
typedef __attribute__((ext_vector_type(4))) float f32x4;

__device__ __forceinline__ float4 f4add(float4 a, float4 b) {
    return make_float4(a.x + b.x, a.y + b.y, a.z + b.z, a.w + b.w);
}
__device__ __forceinline__ float4 f4fma(float4 acc, float4 v, float4 e) {
    return make_float4(fmaf(v.x, e.x, acc.x), fmaf(v.y, e.y, acc.y),
                       fmaf(v.z, e.z, acc.z), fmaf(v.w, e.w, acc.w));
}
__device__ __forceinline__ ushortT bf16_rne(float x) {
    unsigned u = __float_as_uint(x);
    return (ushortT)((u + 0x7fffu + ((u >> 16) & 1u)) >> 16);
}
__device__ __forceinline__ float bf16_to_f(ushortT h) {
    return __uint_as_float(((unsigned)h) << 16);
}
__device__ __forceinline__ short4v f4_to_bf4(float4 v) {
    short4v r;
    r[0] = (short)bf16_rne(v.x);
    r[1] = (short)bf16_rne(v.y);
    r[2] = (short)bf16_rne(v.z);
    r[3] = (short)bf16_rne(v.w);
    return r;
}
__device__ __forceinline__ float4 bf4_to_f4(short4v h) {
    return make_float4(bf16_to_f((ushortT)h[0]), bf16_to_f((ushortT)h[1]),
                       bf16_to_f((ushortT)h[2]), bf16_to_f((ushortT)h[3]));
}

// fragment-interleaved offset (ushort units) for element (row, col)
__device__ __forceinline__ size_t frag_off(int row, int col) {
    return ((size_t)((row >> 4) * 19 + (col >> 5)) * 64
            + (row & 15) + 16 * ((col >> 3) & 3)) * 8 + (col & 7);
}

// ---------------------------------------------------------------------------
// Table conversion: fp32 [rows][600] -> bf16 [rows][600]
// ---------------------------------------------------------------------------
__global__ void k_conv_tab(const float4* __restrict__ src,
                           ushortT* __restrict__ dst, int total8) {
    int idx = blockIdx.x * blockDim.x + threadIdx.x;   // one per 8 elements
    if (idx >= total8) return;
    float4 a = src[idx * 2];
    float4 b = src[idx * 2 + 1];
    short8 h;
    h[0] = (short)bf16_rne(a.x); h[1] = (short)bf16_rne(a.y);
    h[2] = (short)bf16_rne(a.z); h[3] = (short)bf16_rne(a.w);
    h[4] = (short)bf16_rne(b.x); h[5] = (short)bf16_rne(b.y);
    h[6] = (short)bf16_rne(b.z); h[7] = (short)bf16_rne(b.w);
    *(short8*)(dst + (size_t)idx * 8) = h;
}

// ---------------------------------------------------------------------------
// K1: node embedding = sum of 5 table lookups, SINGLE-bf16 row-major out.
// ---------------------------------------------------------------------------
__global__ void k_node_embed_b(const int* __restrict__ atom,
                               const float4* __restrict__ Wa,
                               const float4* __restrict__ Wh,
                               const float4* __restrict__ War,
                               const float4* __restrict__ Wc,
                               const float4* __restrict__ Wch,
                               ushortT* __restrict__ out, int N) {
    int idx = blockIdx.x * blockDim.x + threadIdx.x;
    int total = N * Q4;
    if (idx >= total) return;
    int n = idx / Q4;
    int q = idx - n * Q4;
    const int* a = atom + n * 5;
    float4 r = Wa[a[0] * Q4 + q];
    r = f4add(r, Wh [a[1] * Q4 + q]);
    r = f4add(r, War[a[2] * Q4 + q]);
    r = f4add(r, Wc [a[3] * Q4 + q]);
    r = f4add(r, Wch[a[4] * Q4 + q]);
    *(short4v*)(out + (size_t)n * EMB + q * 4) = f4_to_bf4(r);
}

// ---------------------------------------------------------------------------
// CSR build: histogram -> 3-level parallel scan -> scatter
// ---------------------------------------------------------------------------
__global__ void k_hist(const int* __restrict__ bdst, int* __restrict__ counts, int E) {
    int i = blockIdx.x * blockDim.x + threadIdx.x;
    if (i < E) atomicAdd(&counts[bdst[i]], 1);
}

__global__ __launch_bounds__(256) void k_scan_l1(const int* __restrict__ counts,
                                                 int* __restrict__ offsets,
                                                 int* __restrict__ blocksums, int N) {
    __shared__ int s[256];
    int t = threadIdx.x;
    int i = blockIdx.x * 256 + t;
    int v = (i < N) ? counts[i] : 0;
    s[t] = v;
    __syncthreads();
#pragma unroll
    for (int off = 1; off < 256; off <<= 1) {
        int x = (t >= off) ? s[t - off] : 0;
        __syncthreads();
        s[t] += x;
        __syncthreads();
    }
    if (i < N) offsets[i] = s[t] - v;
    if (t == 255) blocksums[blockIdx.x] = s[255];
}

__global__ __launch_bounds__(256) void k_scan_l2(int* __restrict__ blocksums,
                                                 int* __restrict__ blockpref, int nb) {
    __shared__ int s[256];
    int t = threadIdx.x;
    int v = (t < nb) ? blocksums[t] : 0;
    s[t] = v;
    __syncthreads();
#pragma unroll
    for (int off = 1; off < 256; off <<= 1) {
        int x = (t >= off) ? s[t - off] : 0;
        __syncthreads();
        s[t] += x;
        __syncthreads();
    }
    if (t < nb) blockpref[t] = s[t] - v;
}

__global__ __launch_bounds__(256) void k_scan_l3(int* __restrict__ offsets,
                                                 int* __restrict__ cursor,
                                                 const int* __restrict__ blockpref, int N) {
    int i = blockIdx.x * 256 + threadIdx.x;
    if (i < N) {
        int o = offsets[i] + blockpref[blockIdx.x];
        offsets[i] = o;
        cursor[i]  = o;
    }
}

__global__ void k_scatter(const int* __restrict__ bdst, int* __restrict__ cursor,
                          int* __restrict__ edge_list, int E) {
    int i = blockIdx.x * blockDim.x + threadIdx.x;
    if (i < E) {
        int pos = atomicAdd(&cursor[bdst[i]], 1);
        edge_list[pos] = i;
    }
}

// ---------------------------------------------------------------------------
// MP gather loop: meta 2 ahead; src-row values 1 ahead; bf16 tables at use.
// All value streams bf16 (8B/lane) -- table bytes halved vs fp32.
// ---------------------------------------------------------------------------
#define MP_BODY                                                                \
    int start = offsets[d], cnt = counts[d];                                   \
    int s0 = 0, t00 = 0, t01 = 0, s1 = 0, t10 = 0, t11 = 0;                    \
    if (cnt > 0) {                                                             \
        int e = edge_list[start];                                              \
        s0 = bsrc[e]; t00 = battr[2 * e]; t01 = battr[2 * e + 1];              \
    }                                                                          \
    if (cnt > 1) {                                                             \
        int e = edge_list[start + 1];                                          \
        s1 = bsrc[e]; t10 = battr[2 * e]; t11 = battr[2 * e + 1];              \
    }                                                                          \
    short4v cs1 = {0, 0, 0, 0}, cs2 = {0, 0, 0, 0};                            \
    if (cnt > 0) {                                                             \
        const ushortT* sr = in + (size_t)s0 * EMB;                             \
        cs1 = *(const short4v*)(sr + q1 * 4);                                  \
        if (has2) cs2 = *(const short4v*)(sr + q2 * 4);                        \
    }                                                                          \
    const ushortT* slA = Tsla + (size_t)atom[d * 5] * EMB;                     \
    const ushortT* inr = in + (size_t)d * EMB;                                 \
    float4 acc1 = make_float4(0, 0, 0, 0), acc2 = acc1;                        \
    acc1 = f4fma(acc1, bf4_to_f4(*(const short4v*)(inr + q1 * 4)),             \
                 f4add(bf4_to_f4(*(const short4v*)(slA + q1 * 4)),             \
                       bf4_to_f4(*(const short4v*)(Tsl + q1 * 4))));           \
    if (has2) acc2 = f4fma(acc2, bf4_to_f4(*(const short4v*)(inr + q2 * 4)),   \
                           f4add(bf4_to_f4(*(const short4v*)(slA + q2 * 4)),   \
                                 bf4_to_f4(*(const short4v*)(Tsl + q2 * 4)))); \
    for (int k = 0; k < cnt; k++) {                                            \
        short4v xs1 = cs1, xs2 = cs2;                                          \
        int ct0 = t00, ct1 = t01;                                              \
        s0 = s1; t00 = t10; t01 = t11;                                         \
        if (k + 2 < cnt) {                                                     \
            int e = edge_list[start + k + 2];                                  \
            s1 = bsrc[e]; t10 = battr[2 * e]; t11 = battr[2 * e + 1];          \
        }                                                                      \
        if (k + 1 < cnt) {                                                     \
            const ushortT* sr = in + (size_t)s0 * EMB;                         \
            cs1 = *(const short4v*)(sr + q1 * 4);                              \
            if (has2) cs2 = *(const short4v*)(sr + q2 * 4);                    \
        }                                                                      \
        const ushortT* e0 = Tbt  + (size_t)ct0 * EMB;                          \
        const ushortT* e1 = Tbai + (size_t)ct1 * EMB;                          \
        acc1 = f4fma(acc1, bf4_to_f4(xs1),                                     \
                     f4add(bf4_to_f4(*(const short4v*)(e0 + q1 * 4)),          \
                           bf4_to_f4(*(const short4v*)(e1 + q1 * 4))));        \
        if (has2) acc2 = f4fma(acc2, bf4_to_f4(xs2),                           \
                     f4add(bf4_to_f4(*(const short4v*)(e0 + q2 * 4)),          \
                           bf4_to_f4(*(const short4v*)(e1 + q2 * 4))));        \
    }

// ---------------------------------------------------------------------------
// K2a: MP round 1. bf16 rows in, bf16 rows out. TWO waves per dest node.
// ---------------------------------------------------------------------------
__global__ __launch_bounds__(256) void k_mp_gather_b(
        const int* __restrict__ bsrc, const int* __restrict__ battr,
        const int* __restrict__ atom,
        const int* __restrict__ offsets, const int* __restrict__ counts,
        const int* __restrict__ edge_list,
        const ushortT* __restrict__ Tbt, const ushortT* __restrict__ Tbai,
        const ushortT* __restrict__ Tsla, const ushortT* __restrict__ Tsl,
        const ushortT* __restrict__ in, ushortT* __restrict__ out, int N) {
    int wid  = (int)((blockIdx.x * blockDim.x + threadIdx.x) >> 6);
    int lane = threadIdx.x & 63;
    int d    = wid >> 1;
    int half = wid & 1;
    if (d >= N) return;
    int q1 = 75 * half + lane;
    int q2 = q1 + 64;
    bool has2 = lane < 11;

    MP_BODY

    ushortT* orow = out + (size_t)d * EMB;
    *(short4v*)(orow + q1 * 4) = f4_to_bf4(acc1);
    if (has2) *(short4v*)(orow + q2 * 4) = f4_to_bf4(acc2);
}

// ---------------------------------------------------------------------------
// K2b: MP round 2. bf16 rows in, relu + single-bf16 frag-interleaved out.
// ---------------------------------------------------------------------------
__device__ __forceinline__ void frag_store4h(ushortT* __restrict__ hi,
                                             int d, int q, float4 v) {
    int kc = q >> 3, ks = (q >> 1) & 3, halfw = q & 1;
    size_t off = ((size_t)((d >> 4) * 19 + kc) * 64 + (d & 15) + 16 * ks) * 8
                 + halfw * 4;
    float vv[4] = {v.x, v.y, v.z, v.w};
    short4v h4;
#pragma unroll
    for (int j = 0; j < 4; j++)
        h4[j] = (short)bf16_rne(fmaxf(vv[j], 0.f));
    *(short4v*)(hi + off) = h4;
}

__global__ __launch_bounds__(256) void k_mp_gather_rs(
        const int* __restrict__ bsrc, const int* __restrict__ battr,
        const int* __restrict__ atom,
        const int* __restrict__ offsets, const int* __restrict__ counts,
        const int* __restrict__ edge_list,
        const ushortT* __restrict__ Tbt, const ushortT* __restrict__ Tbai,
        const ushortT* __restrict__ Tsla, const ushortT* __restrict__ Tsl,
        const ushortT* __restrict__ in,
        ushortT* __restrict__ hi, int N) {
    int wid  = (int)((blockIdx.x * blockDim.x + threadIdx.x) >> 6);
    int lane = threadIdx.x & 63;
    int d    = wid >> 1;
    int half = wid & 1;
    if (d >= N) return;
    int q1 = 75 * half + lane;
    int q2 = q1 + 64;
    bool has2 = lane < 11;

    MP_BODY

    frag_store4h(hi, d, q1, acc1);
    if (has2) frag_store4h(hi, d, q2, acc2);
    if (half == 0 && lane == 31) {   // zero K-pad cols 600..607 (kc=18, ks=3)
        size_t off = ((size_t)((d >> 4) * 19 + 18) * 64 + (d & 15) + 48) * 8;
        short8 z = {0, 0, 0, 0, 0, 0, 0, 0};
        *(short8*)(hi + off) = z;
    }
}

// ---------------------------------------------------------------------------
// Weight split to FRAGMENT-INTERLEAVED single bf16.
// ---------------------------------------------------------------------------
__global__ void k_split_w_frag(const float* __restrict__ src,
                               short8* __restrict__ dst,
                               int rows_in, int cb_count) {
    int idx = blockIdx.x * blockDim.x + threadIdx.x;
    int total = cb_count * 19 * 64;
    if (idx >= total) return;
    int lane = idx & 63;
    int tile = idx >> 6;
    int cb = tile / 19, kc = tile - cb * 19;
    int col = cb * 16 + (lane & 15);
    int k0  = kc * 32 + (lane >> 4) * 8;
    short8 h;
#pragma unroll
    for (int j = 0; j < 8; j++) {
        int k = k0 + j;
        float x = (col < rows_in && k < 600) ? src[(size_t)col * 600 + k] : 0.f;
        h[j] = (short)bf16_rne(x);
    }
    dst[idx] = h;
}

// ---------------------------------------------------------------------------
// Register GEMM core (single bf16 x single bf16): 128x128 block, 4 waves,
// no LDS/barriers. 16 MFMA + 8 loads per kc per wave.
// ---------------------------------------------------------------------------
struct FragSet { short8 a[4], b[4]; };

__device__ __forceinline__ void frag_load(FragSet& f,
        const short8* __restrict__ Af, const short8* __restrict__ Bf,
        int aBase, int bBase, int kc) {
    int ak = aBase + kc * 64;
    int bk = bBase + kc * 64;
#pragma unroll
    for (int i = 0; i < 4; i++) {
        f.a[i] = Af[ak + i * 1216];   // 1216 = 19*64 short8 per row-block
        f.b[i] = Bf[bk + i * 1216];
    }
}

__device__ __forceinline__ void frag_mfma(const FragSet& f, f32x4 acc[4][4]) {
#pragma unroll
    for (int i = 0; i < 4; i++)
#pragma unroll
        for (int j = 0; j < 4; j++)
            acc[i][j] = __builtin_amdgcn_mfma_f32_16x16x32_bf16(f.a[i], f.b[j], acc[i][j], 0, 0, 0);
}

__device__ __forceinline__ void gemm_core_reg(
        const short8* __restrict__ Af, const short8* __restrict__ Bf,
        int aBase, int bBase, f32x4 acc[4][4]) {
    for (int kc = 0; kc < 19; kc++) {
        FragSet f;
        frag_load(f, Af, Bf, aBase, bBase, kc);
        frag_mfma(f, acc);
    }
}

// m204 bijective XCD swizzle
__device__ __forceinline__ void decode_wg(int ncb, int& rowblk, int& colblk) {
    int nwg  = gridDim.x;
    int orig = blockIdx.x;
    int q = nwg >> 3, r = nwg & 7;
    int xcd = orig & 7, rank = orig >> 3;
    int wgid = (xcd < r ? xcd * (q + 1) : r * (q + 1) + (xcd - r) * q) + rank;
    rowblk = wgid / ncb;
    colblk = wgid - rowblk * ncb;
}

// GEMM1: H = relu(A @ W1^T + b1) -> Hf (single bf16, frag-interleaved). grid Mb*5.
__global__ __launch_bounds__(256, 4) void k_gemm1r(
        const short8* __restrict__ Af, const short8* __restrict__ Wf,
        const float* __restrict__ b1,
        ushortT* __restrict__ Hf, int N) {
    int rowblk, colblk;
    decode_wg(5, rowblk, colblk);
    int row0 = rowblk * 128;
    int col0 = colblk * 128;
    int t = threadIdx.x, w = t >> 6, l = t & 63;
    int wr = w >> 1, wc = w & 1, fr = l & 15, fq = l >> 4;

    int aBase = (rowblk * 8 + wr * 4) * 1216 + l;
    int bBase = (colblk * 8 + wc * 4) * 1216 + l;
    f32x4 acc[4][4];
#pragma unroll
    for (int i = 0; i < 4; i++)
#pragma unroll
        for (int j = 0; j < 4; j++) acc[i][j] = f32x4{0.f, 0.f, 0.f, 0.f};
    gemm_core_reg(Af, Wf, aBase, bBase, acc);

#pragma unroll
    for (int i = 0; i < 4; i++) {
#pragma unroll
        for (int j = 0; j < 4; j++) {
            int col = col0 + wc * 64 + j * 16 + fr;
            float bias = (col < 600) ? b1[col] : 0.f;
#pragma unroll
            for (int r = 0; r < 4; r++) {
                int row = row0 + wr * 64 + i * 16 + fq * 4 + r;
                if (row >= N) continue;
                if (col < 600) {
                    float x = fmaxf(acc[i][j][r] + bias, 0.f);
                    Hf[frag_off(row, col)] = bf16_rne(x);
                } else if (col < KP) {
                    Hf[frag_off(row, col)] = 0;
                }
            }
        }
    }
}

// GEMM2: energy += sum_col relu(H @ W2^T + b2) * W3. grid Mb*3.
__global__ __launch_bounds__(256, 4) void k_gemm2r(
        const short8* __restrict__ Af, const short8* __restrict__ Wf,
        const float* __restrict__ b2, const float* __restrict__ W3,
        float* __restrict__ energy, int N) {
    __shared__ float sE[128];
    int rowblk, colblk;
    decode_wg(3, rowblk, colblk);
    int row0 = rowblk * 128;
    int col0 = colblk * 128;
    int t = threadIdx.x, w = t >> 6, l = t & 63;
    int wr = w >> 1, wc = w & 1, fr = l & 15, fq = l >> 4;

    int aBase = (rowblk * 8 + wr * 4) * 1216 + l;
    int bBase = (colblk * 8 + wc * 4) * 1216 + l;
    f32x4 acc[4][4];
#pragma unroll
    for (int i = 0; i < 4; i++)
#pragma unroll
        for (int j = 0; j < 4; j++) acc[i][j] = f32x4{0.f, 0.f, 0.f, 0.f};
    gemm_core_reg(Af, Wf, aBase, bBase, acc);

    if (t < 128) sE[t] = 0.f;
    __syncthreads();
#pragma unroll
    for (int i = 0; i < 4; i++) {
        float p[4] = {0.f, 0.f, 0.f, 0.f};
#pragma unroll
        for (int j = 0; j < 4; j++) {
            int col = col0 + wc * 64 + j * 16 + fr;
            if (col < 300) {
                float bias = b2[col];
                float wv   = W3[col];
#pragma unroll
                for (int r = 0; r < 4; r++)
                    p[r] += fmaxf(acc[i][j][r] + bias, 0.f) * wv;
            }
        }
#pragma unroll
        for (int r = 0; r < 4; r++) {
            float v = p[r];
            v += __shfl_xor(v, 1, 64);
            v += __shfl_xor(v, 2, 64);
            v += __shfl_xor(v, 4, 64);
            v += __shfl_xor(v, 8, 64);
            p[r] = v;
        }
        if (fr == 0) {
#pragma unroll
            for (int r = 0; r < 4; r++)
                atomicAdd(&sE[wr * 64 + i * 16 + fq * 4 + r], p[r]);
        }
    }
    __syncthreads();
    if (t < 128) {
        int row = row0 + t;
        if (row < N) atomicAdd(&energy[row], sE[t]);
    }
}

// ---------------------------------------------------------------------------
// K5: per-graph pool. batch sorted -> wave-segmented reduce, few atomics.
// ---------------------------------------------------------------------------
__global__ void k_pool(const float* __restrict__ energy, const int* __restrict__ batch,
                       float* __restrict__ dg, int N) {
    int i = blockIdx.x * blockDim.x + threadIdx.x;
    int lane = threadIdx.x & 63;
    float v = (i < N) ? energy[i] : 0.f;
    int   b = (i < N) ? batch[i]  : -1;
#pragma unroll
    for (int off = 1; off < 64; off <<= 1) {
        float vv = __shfl_down(v, off, 64);
        int   bb = __shfl_down(b, off, 64);
        if (lane + off < 64 && bb == b) v += vv;
    }
    int pb = __shfl_up(b, 1, 64);
    if (i < N && (lane == 0 || pb != b)) atomicAdd(&dg[b], v);
}

extern "C" void kernel_launch(void* const* d_in, const int* in_sizes, int n_in,
                              void* d_out, int out_size, void* d_ws, size_t ws_size,
                              hipStream_t stream) {
    const int* atom       = (const int*)d_in[0];
    const int* bond_index = (const int*)d_in[1];
    const int* bond_attr  = (const int*)d_in[2];
    const int* batch      = (const int*)d_in[3];
    const float* Wa   = (const float*)d_in[4];
    const float* Wh   = (const float*)d_in[5];
    const float* War  = (const float*)d_in[6];
    const float* Wc   = (const float*)d_in[7];
    const float* Wch  = (const float*)d_in[8];
    const float* Wbt  = (const float*)d_in[9];
    const float* Wbai = (const float*)d_in[10];
    const float* Wsla = (const float*)d_in[11];
    const float* Wsl  = (const float*)d_in[12];
    const float* W1   = (const float*)d_in[13];
    const float* b1   = (const float*)d_in[14];
    const float* W2   = (const float*)d_in[15];
    const float* b2   = (const float*)d_in[16];
    const float* W3   = (const float*)d_in[17];

    int N = in_sizes[0] / 5;    // 50000
    int E = in_sizes[1] / 2;    // 100000
    int rBT  = in_sizes[9]  / EMB;   // 22
    int rBAI = in_sizes[10] / EMB;   // 119
    int rSLA = in_sizes[11] / EMB;   // 119
    int Mb = (N + 127) / 128;   // 391
    int Npad = Mb * 128;        // 50048
    int nTiles = Npad / 16;     // 3128 row-blocks
    int nb = (N + 255) / 256;   // 196 scan blocks

    size_t regionBytes = (size_t)Npad * KP * 4;
    char* base = (char*)d_ws;
    ushortT* nodeAb = (ushortT*)base;                  // region0: embed out (bf16 rows)
    ushortT* nodeBh = (ushortT*)(base + regionBytes);  // region1: mp1 out (bf16 rows)
    short8* Af = (short8*)nodeAb;                      // region0 reuse: mp2 out frags
    short8* Hf = (short8*)nodeBh;                      // region1 reuse: gemm1 out frags
    char* tail = base + 2 * regionBytes;
    float* energy  = (float*)tail;
    int* counts    = (int*)(energy + N);
    int* offsets   = counts + N;
    int* cursor    = offsets + N;
    int* edge_list = cursor + N;
    short8* W1f    = (short8*)(edge_list + E);         // 40*19*64 tiles
    short8* W2f    = W1f + 40 * 19 * 64;               // 24*19*64 tiles
    int* blocksums = (int*)(W2f + 24 * 19 * 64);
    int* blockpref = blocksums + 256;
    ushortT* Tbt   = (ushortT*)(blockpref + 256);      // bf16 tables
    ushortT* Tbai  = Tbt  + (size_t)rBT  * EMB;
    ushortT* Tsla  = Tbai + (size_t)rBAI * EMB;
    ushortT* Tsl   = Tsla + (size_t)rSLA * EMB;

    const int* bsrc = bond_index;
    const int* bdst = bond_index + E;

    // CSR build (dst -> edges)
    hipMemsetAsync(counts, 0, (size_t)N * sizeof(int), stream);
    k_hist<<<(E + 255) / 256, 256, 0, stream>>>(bdst, counts, E);
    k_scan_l1<<<nb, 256, 0, stream>>>(counts, offsets, blocksums, N);
    k_scan_l2<<<1, 256, 0, stream>>>(blocksums, blockpref, nb);
    k_scan_l3<<<nb, 256, 0, stream>>>(offsets, cursor, blockpref, N);
    k_scatter<<<(E + 255) / 256, 256, 0, stream>>>(bdst, cursor, edge_list, E);

    // table conversions to bf16 rows
    {
        int t8;
        t8 = rBT  * 75; k_conv_tab<<<(t8 + 255) / 256, 256, 0, stream>>>((const float4*)Wbt,  Tbt,  t8);
        t8 = rBAI * 75; k_conv_tab<<<(t8 + 255) / 256, 256, 0, stream>>>((const float4*)Wbai, Tbai, t8);
        t8 = rSLA * 75; k_conv_tab<<<(t8 + 255) / 256, 256, 0, stream>>>((const float4*)Wsla, Tsla, t8);
        t8 = 75;        k_conv_tab<<<1, 128, 0, stream>>>((const float4*)Wsl,  Tsl,  t8);
    }

    // weight splits to fragment-interleaved single bf16
    k_split_w_frag<<<(40 * 19 * 64 + 255) / 256, 256, 0, stream>>>(W1, W1f, 600, 40);
    k_split_w_frag<<<(24 * 19 * 64 + 255) / 256, 256, 0, stream>>>(W2, W2f, 300, 24);

    // K1: node embedding -> nodeAb (bf16 rows)
    {
        int total = N * Q4;
        k_node_embed_b<<<(total + 255) / 256, 256, 0, stream>>>(
            atom, (const float4*)Wa, (const float4*)Wh, (const float4*)War,
            (const float4*)Wc, (const float4*)Wch, nodeAb, N);
    }

    int mpblocks = (2 * N * 64 + 255) / 256;   // two waves per node
    // round 1: nodeAb (bf16) -> nodeBh (bf16 rows)
    k_mp_gather_b<<<mpblocks, 256, 0, stream>>>(bsrc, bond_attr, atom,
        offsets, counts, edge_list,
        Tbt, Tbai, Tsla, Tsl, nodeAb, nodeBh, N);

    // zero A-frag pad tiles (rows N..Npad; region0 embed data is dead now)
    {
        int firstPad = N / 16;
        size_t offB  = (size_t)firstPad * 1216 * 16;
        size_t cntB  = (size_t)(nTiles - firstPad) * 1216 * 16;
        if (cntB) hipMemsetAsync((char*)Af + offB, 0, cntB, stream);
    }

    // round 2 fused with relu + single-bf16 frag cast: nodeBh -> Af
    k_mp_gather_rs<<<mpblocks, 256, 0, stream>>>(bsrc, bond_attr, atom,
        offsets, counts, edge_list,
        Tbt, Tbai, Tsla, Tsl, nodeBh, (ushortT*)Af, N);

    // GEMM1: Af x W1f -> Hf (region1; nodeBh dead)
    k_gemm1r<<<Mb * 5, 256, 0, stream>>>(Af, W1f, b1, (ushortT*)Hf, N);

    // GEMM2: Hf x W2f (+b2, W3) -> energy (atomic accumulate)
    hipMemsetAsync(energy, 0, (size_t)N * sizeof(float), stream);
    k_gemm2r<<<Mb * 3, 256, 0, stream>>>(Hf, W2f, b2, W3, energy, N);

    // pool
    hipMemsetAsync(d_out, 0, (size_t)out_size * sizeof(float), stream);
    k_pool<<<(N + 255) / 256, 256, 0, stream>>>(energy, batch, (float*)d_out, N);
}

// Round 18
// 314.420 us; speedup vs baseline: 1.1142x; 1.1142x over previous
//
#include <hip/hip_runtime.h>

#define EMB 600
#define Q4  150   // EMB / 4
#define KP  608   // K padded (19 * 32)

typedef unsigned short ushortT;
typedef __attribute__((ext_vector_type(8))) short short8;
typedef __attribute__((ext_vector_type(4))) short short4v;
typedef __attribute__((ext_vector_type(4))) float f32x4;

__device__ __forceinline__ float4 f4add(float4 a, float4 b) {
    return make_float4(a.x + b.x, a.y + b.y, a.z + b.z, a.w + b.w);
}
__device__ __forceinline__ float4 f4fma(float4 acc, float4 v, float4 e) {
    return make_float4(fmaf(v.x, e.x, acc.x), fmaf(v.y, e.y, acc.y),
                       fmaf(v.z, e.z, acc.z), fmaf(v.w, e.w, acc.w));
}
__device__ __forceinline__ ushortT bf16_rne(float x) {
    unsigned u = __float_as_uint(x);
    return (ushortT)((u + 0x7fffu + ((u >> 16) & 1u)) >> 16);
}
__device__ __forceinline__ float bf16_to_f(ushortT h) {
    return __uint_as_float(((unsigned)h) << 16);
}
__device__ __forceinline__ short4v f4_to_bf4(float4 v) {
    short4v r;
    r[0] = (short)bf16_rne(v.x);
    r[1] = (short)bf16_rne(v.y);
    r[2] = (short)bf16_rne(v.z);
    r[3] = (short)bf16_rne(v.w);
    return r;
}
__device__ __forceinline__ float4 bf4_to_f4(short4v h) {
    return make_float4(bf16_to_f((ushortT)h[0]), bf16_to_f((ushortT)h[1]),
                       bf16_to_f((ushortT)h[2]), bf16_to_f((ushortT)h[3]));
}

// fragment-interleaved offset (ushort units) for element (row, col)
__device__ __forceinline__ size_t frag_off(int row, int col) {
    return ((size_t)((row >> 4) * 19 + (col >> 5)) * 64
            + (row & 15) + 16 * ((col >> 3) & 3)) * 8 + (col & 7);
}

// ---------------------------------------------------------------------------
// Combo tables: Tcombo[c][600] = bf16(Wbt[c/rBAI] + Wbai[c%rBAI]);
//               Tslc[r][600]  = bf16(Wsla[r] + Wsl[0])
// ---------------------------------------------------------------------------
__global__ void k_combo(const float* __restrict__ Wbt, const float* __restrict__ Wbai,
                        ushortT* __restrict__ dst, int rBAI, int total) {
    int idx = blockIdx.x * blockDim.x + threadIdx.x;   // one per 8 elements
    if (idx >= total) return;
    int row = idx / 75, u = idx - row * 75;
    int bt = row / rBAI, bai = row - bt * rBAI;
    const float* pa = Wbt  + (size_t)bt  * EMB + u * 8;
    const float* pb = Wbai + (size_t)bai * EMB + u * 8;
    short8 h;
#pragma unroll
    for (int j = 0; j < 8; j++)
        h[j] = (short)bf16_rne(pa[j] + pb[j]);
    *(short8*)(dst + (size_t)row * EMB + u * 8) = h;
}

__global__ void k_slc(const float* __restrict__ Wsla, const float* __restrict__ Wsl,
                      ushortT* __restrict__ dst, int total) {
    int idx = blockIdx.x * blockDim.x + threadIdx.x;
    if (idx >= total) return;
    int row = idx / 75, u = idx - row * 75;
    const float* pa = Wsla + (size_t)row * EMB + u * 8;
    const float* pb = Wsl + u * 8;
    short8 h;
#pragma unroll
    for (int j = 0; j < 8; j++)
        h[j] = (short)bf16_rne(pa[j] + pb[j]);
    *(short8*)(dst + (size_t)row * EMB + u * 8) = h;
}

// ---------------------------------------------------------------------------
// K1: node embedding = sum of 5 table lookups, SINGLE-bf16 row-major out.
// ---------------------------------------------------------------------------
__global__ void k_node_embed_b(const int* __restrict__ atom,
                               const float4* __restrict__ Wa,
                               const float4* __restrict__ Wh,
                               const float4* __restrict__ War,
                               const float4* __restrict__ Wc,
                               const float4* __restrict__ Wch,
                               ushortT* __restrict__ out, int N) {
    int idx = blockIdx.x * blockDim.x + threadIdx.x;
    int total = N * Q4;
    if (idx >= total) return;
    int n = idx / Q4;
    int q = idx - n * Q4;
    const int* a = atom + n * 5;
    float4 r = Wa[a[0] * Q4 + q];
    r = f4add(r, Wh [a[1] * Q4 + q]);
    r = f4add(r, War[a[2] * Q4 + q]);
    r = f4add(r, Wc [a[3] * Q4 + q]);
    r = f4add(r, Wch[a[4] * Q4 + q]);
    *(short4v*)(out + (size_t)n * EMB + q * 4) = f4_to_bf4(r);
}

// ---------------------------------------------------------------------------
// CSR build: histogram -> 3-level parallel scan -> scatter (src+cidx direct)
// ---------------------------------------------------------------------------
__global__ void k_hist(const int* __restrict__ bdst, int* __restrict__ counts, int E) {
    int i = blockIdx.x * blockDim.x + threadIdx.x;
    if (i < E) atomicAdd(&counts[bdst[i]], 1);
}

__global__ __launch_bounds__(256) void k_scan_l1(const int* __restrict__ counts,
                                                 int* __restrict__ offsets,
                                                 int* __restrict__ blocksums, int N) {
    __shared__ int s[256];
    int t = threadIdx.x;
    int i = blockIdx.x * 256 + t;
    int v = (i < N) ? counts[i] : 0;
    s[t] = v;
    __syncthreads();
#pragma unroll
    for (int off = 1; off < 256; off <<= 1) {
        int x = (t >= off) ? s[t - off] : 0;
        __syncthreads();
        s[t] += x;
        __syncthreads();
    }
    if (i < N) offsets[i] = s[t] - v;
    if (t == 255) blocksums[blockIdx.x] = s[255];
}

__global__ __launch_bounds__(256) void k_scan_l2(int* __restrict__ blocksums,
                                                 int* __restrict__ blockpref, int nb) {
    __shared__ int s[256];
    int t = threadIdx.x;
    int v = (t < nb) ? blocksums[t] : 0;
    s[t] = v;
    __syncthreads();
#pragma unroll
    for (int off = 1; off < 256; off <<= 1) {
        int x = (t >= off) ? s[t - off] : 0;
        __syncthreads();
        s[t] += x;
        __syncthreads();
    }
    if (t < nb) blockpref[t] = s[t] - v;
}

__global__ __launch_bounds__(256) void k_scan_l3(int* __restrict__ offsets,
                                                 int* __restrict__ cursor,
                                                 const int* __restrict__ blockpref, int N) {
    int i = blockIdx.x * 256 + threadIdx.x;
    if (i < N) {
        int o = offsets[i] + blockpref[blockIdx.x];
        offsets[i] = o;
        cursor[i]  = o;
    }
}

__global__ void k_scatter2(const int* __restrict__ bsrc, const int* __restrict__ bdst,
                           const int* __restrict__ battr, int* __restrict__ cursor,
                           int* __restrict__ src_list, int* __restrict__ cidx_list,
                           int E, int rBAI) {
    int i = blockIdx.x * blockDim.x + threadIdx.x;
    if (i < E) {
        int pos = atomicAdd(&cursor[bdst[i]], 1);
        src_list[pos]  = bsrc[i];
        cidx_list[pos] = battr[2 * i] * rBAI + battr[2 * i + 1];
    }
}

// ---------------------------------------------------------------------------
// MP gather loop: CSR-ordered src/cidx (2 sequential int loads per edge);
// one bf16 combo-table row per edge; src-row values prefetched 1 ahead.
// ---------------------------------------------------------------------------
#define MP_BODY                                                                \
    int start = offsets[d], cnt = counts[d];                                   \
    int s0 = 0, c0 = 0, s1 = 0, c1 = 0;                                        \
    if (cnt > 0) { s0 = src_list[start]; c0 = cidx_list[start]; }              \
    if (cnt > 1) { s1 = src_list[start + 1]; c1 = cidx_list[start + 1]; }      \
    short4v cs1 = {0, 0, 0, 0}, cs2 = {0, 0, 0, 0};                            \
    if (cnt > 0) {                                                             \
        const ushortT* sr = in + (size_t)s0 * EMB;                             \
        cs1 = *(const short4v*)(sr + q1 * 4);                                  \
        if (has2) cs2 = *(const short4v*)(sr + q2 * 4);                        \
    }                                                                          \
    const ushortT* slA = Tslc + (size_t)atom[d * 5] * EMB;                     \
    const ushortT* inr = in + (size_t)d * EMB;                                 \
    float4 acc1 = make_float4(0, 0, 0, 0), acc2 = acc1;                        \
    acc1 = f4fma(acc1, bf4_to_f4(*(const short4v*)(inr + q1 * 4)),             \
                 bf4_to_f4(*(const short4v*)(slA + q1 * 4)));                  \
    if (has2) acc2 = f4fma(acc2, bf4_to_f4(*(const short4v*)(inr + q2 * 4)),   \
                           bf4_to_f4(*(const short4v*)(slA + q2 * 4)));        \
    for (int k = 0; k < cnt; k++) {                                            \
        short4v xs1 = cs1, xs2 = cs2;                                          \
        int cc = c0;                                                           \
        s0 = s1; c0 = c1;                                                      \
        if (k + 2 < cnt) { s1 = src_list[start + k + 2];                       \
                           c1 = cidx_list[start + k + 2]; }                    \
        if (k + 1 < cnt) {                                                     \
            const ushortT* sr = in + (size_t)s0 * EMB;                         \
            cs1 = *(const short4v*)(sr + q1 * 4);                              \
            if (has2) cs2 = *(const short4v*)(sr + q2 * 4);                    \
        }                                                                      \
        const ushortT* ce = Tcombo + (size_t)cc * EMB;                         \
        acc1 = f4fma(acc1, bf4_to_f4(xs1),                                     \
                     bf4_to_f4(*(const short4v*)(ce + q1 * 4)));               \
        if (has2) acc2 = f4fma(acc2, bf4_to_f4(xs2),                           \
                     bf4_to_f4(*(const short4v*)(ce + q2 * 4)));               \
    }

// ---------------------------------------------------------------------------
// K2a: MP round 1. bf16 rows in, bf16 rows out. TWO waves per dest node.
// ---------------------------------------------------------------------------
__global__ __launch_bounds__(256) void k_mp_gather_b(
        const int* __restrict__ src_list, const int* __restrict__ cidx_list,
        const int* __restrict__ atom,
        const int* __restrict__ offsets, const int* __restrict__ counts,
        const ushortT* __restrict__ Tcombo, const ushortT* __restrict__ Tslc,
        const ushortT* __restrict__ in, ushortT* __restrict__ out, int N) {
    int wid  = (int)((blockIdx.x * blockDim.x + threadIdx.x) >> 6);
    int lane = threadIdx.x & 63;
    int d    = wid >> 1;
    int half = wid & 1;
    if (d >= N) return;
    int q1 = 75 * half + lane;
    int q2 = q1 + 64;
    bool has2 = lane < 11;

    MP_BODY

    ushortT* orow = out + (size_t)d * EMB;
    *(short4v*)(orow + q1 * 4) = f4_to_bf4(acc1);
    if (has2) *(short4v*)(orow + q2 * 4) = f4_to_bf4(acc2);
}

// ---------------------------------------------------------------------------
// K2b: MP round 2. bf16 rows in, relu + single-bf16 frag-interleaved out.
// ---------------------------------------------------------------------------
__device__ __forceinline__ void frag_store4h(ushortT* __restrict__ hi,
                                             int d, int q, float4 v) {
    int kc = q >> 3, ks = (q >> 1) & 3, halfw = q & 1;
    size_t off = ((size_t)((d >> 4) * 19 + kc) * 64 + (d & 15) + 16 * ks) * 8
                 + halfw * 4;
    float vv[4] = {v.x, v.y, v.z, v.w};
    short4v h4;
#pragma unroll
    for (int j = 0; j < 4; j++)
        h4[j] = (short)bf16_rne(fmaxf(vv[j], 0.f));
    *(short4v*)(hi + off) = h4;
}

__global__ __launch_bounds__(256) void k_mp_gather_rs(
        const int* __restrict__ src_list, const int* __restrict__ cidx_list,
        const int* __restrict__ atom,
        const int* __restrict__ offsets, const int* __restrict__ counts,
        const ushortT* __restrict__ Tcombo, const ushortT* __restrict__ Tslc,
        const ushortT* __restrict__ in,
        ushortT* __restrict__ hi, int N) {
    int wid  = (int)((blockIdx.x * blockDim.x + threadIdx.x) >> 6);
    int lane = threadIdx.x & 63;
    int d    = wid >> 1;
    int half = wid & 1;
    if (d >= N) return;
    int q1 = 75 * half + lane;
    int q2 = q1 + 64;
    bool has2 = lane < 11;

    MP_BODY

    frag_store4h(hi, d, q1, acc1);
    if (has2) frag_store4h(hi, d, q2, acc2);
    if (half == 0 && lane == 31) {   // zero K-pad cols 600..607 (kc=18, ks=3)
        size_t off = ((size_t)((d >> 4) * 19 + 18) * 64 + (d & 15) + 48) * 8;
        short8 z = {0, 0, 0, 0, 0, 0, 0, 0};
        *(short8*)(hi + off) = z;
    }
}

// ---------------------------------------------------------------------------
// Weight split to FRAGMENT-INTERLEAVED single bf16.
// ---------------------------------------------------------------------------
__global__ void k_split_w_frag(const float* __restrict__ src,
                               short8* __restrict__ dst,
                               int rows_in, int cb_count) {
    int idx = blockIdx.x * blockDim.x + threadIdx.x;
    int total = cb_count * 19 * 64;
    if (idx >= total) return;
    int lane = idx & 63;
    int tile = idx >> 6;
    int cb = tile / 19, kc = tile - cb * 19;
    int col = cb * 16 + (lane & 15);
    int k0  = kc * 32 + (lane >> 4) * 8;
    short8 h;
#pragma unroll
    for (int j = 0; j < 8; j++) {
        int k = k0 + j;
        float x = (col < rows_in && k < 600) ? src[(size_t)col * 600 + k] : 0.f;
        h[j] = (short)bf16_rne(x);
    }
    dst[idx] = h;
}

// ---------------------------------------------------------------------------
// Register GEMM core (single bf16 x single bf16): 128x128 block, 4 waves,
// no LDS/barriers. 16 MFMA + 8 loads per kc per wave.
// ---------------------------------------------------------------------------
struct FragSet { short8 a[4], b[4]; };

__device__ __forceinline__ void frag_load(FragSet& f,
        const short8* __restrict__ Af, const short8* __restrict__ Bf,
        int aBase, int bBase, int kc) {
    int ak = aBase + kc * 64;
    int bk = bBase + kc * 64;
#pragma unroll
    for (int i = 0; i < 4; i++) {
        f.a[i] = Af[ak + i * 1216];   // 1216 = 19*64 short8 per row-block
        f.b[i] = Bf[bk + i * 1216];
    }
}

__device__ __forceinline__ void frag_mfma(const FragSet& f, f32x4 acc[4][4]) {
#pragma unroll
    for (int i = 0; i < 4; i++)
#pragma unroll
        for (int j = 0; j < 4; j++)
            acc[i][j] = __builtin_amdgcn_mfma_f32_16x16x32_bf16(f.a[i], f.b[j], acc[i][j], 0, 0, 0);
}

__device__ __forceinline__ void gemm_core_reg(
        const short8* __restrict__ Af, const short8* __restrict__ Bf,
        int aBase, int bBase, f32x4 acc[4][4]) {
    for (int kc = 0; kc < 19; kc++) {
        FragSet f;
        frag_load(f, Af, Bf, aBase, bBase, kc);
        frag_mfma(f, acc);
    }
}

// m204 bijective XCD swizzle
__device__ __forceinline__ void decode_wg(int ncb, int& rowblk, int& colblk) {
    int nwg  = gridDim.x;
    int orig = blockIdx.x;
    int q = nwg >> 3, r = nwg & 7;
    int xcd = orig & 7, rank = orig >> 3;
    int wgid = (xcd < r ? xcd * (q + 1) : r * (q + 1) + (xcd - r) * q) + rank;
    rowblk = wgid / ncb;
    colblk = wgid - rowblk * ncb;
}

// GEMM1: H = relu(A @ W1^T + b1) -> Hf (single bf16, frag-interleaved). grid Mb*5.
__global__ __launch_bounds__(256, 4) void k_gemm1r(
        const short8* __restrict__ Af, const short8* __restrict__ Wf,
        const float* __restrict__ b1,
        ushortT* __restrict__ Hf, int N) {
    int rowblk, colblk;
    decode_wg(5, rowblk, colblk);
    int row0 = rowblk * 128;
    int col0 = colblk * 128;
    int t = threadIdx.x, w = t >> 6, l = t & 63;
    int wr = w >> 1, wc = w & 1, fr = l & 15, fq = l >> 4;

    int aBase = (rowblk * 8 + wr * 4) * 1216 + l;
    int bBase = (colblk * 8 + wc * 4) * 1216 + l;
    f32x4 acc[4][4];
#pragma unroll
    for (int i = 0; i < 4; i++)
#pragma unroll
        for (int j = 0; j < 4; j++) acc[i][j] = f32x4{0.f, 0.f, 0.f, 0.f};
    gemm_core_reg(Af, Wf, aBase, bBase, acc);

#pragma unroll
    for (int i = 0; i < 4; i++) {
#pragma unroll
        for (int j = 0; j < 4; j++) {
            int col = col0 + wc * 64 + j * 16 + fr;
            float bias = (col < 600) ? b1[col] : 0.f;
#pragma unroll
            for (int r = 0; r < 4; r++) {
                int row = row0 + wr * 64 + i * 16 + fq * 4 + r;
                if (row >= N) continue;
                if (col < 600) {
                    float x = fmaxf(acc[i][j][r] + bias, 0.f);
                    Hf[frag_off(row, col)] = bf16_rne(x);
                } else if (col < KP) {
                    Hf[frag_off(row, col)] = 0;
                }
            }
        }
    }
}

// GEMM2: energy += sum_col relu(H @ W2^T + b2) * W3. grid Mb*3.
__global__ __launch_bounds__(256, 4) void k_gemm2r(
        const short8* __restrict__ Af, const short8* __restrict__ Wf,
        const float* __restrict__ b2, const float* __restrict__ W3,
        float* __restrict__ energy, int N) {
    __shared__ float sE[128];
    int rowblk, colblk;
    decode_wg(3, rowblk, colblk);
    int row0 = rowblk * 128;
    int col0 = colblk * 128;
    int t = threadIdx.x, w = t >> 6, l = t & 63;
    int wr = w >> 1, wc = w & 1, fr = l & 15, fq = l >> 4;

    int aBase = (rowblk * 8 + wr * 4) * 1216 + l;
    int bBase = (colblk * 8 + wc * 4) * 1216 + l;
    f32x4 acc[4][4];
#pragma unroll
    for (int i = 0; i < 4; i++)
#pragma unroll
        for (int j = 0; j < 4; j++) acc[i][j] = f32x4{0.f, 0.f, 0.f, 0.f};
    gemm_core_reg(Af, Wf, aBase, bBase, acc);

    if (t < 128) sE[t] = 0.f;
    __syncthreads();
#pragma unroll
    for (int i = 0; i < 4; i++) {
        float p[4] = {0.f, 0.f, 0.f, 0.f};
#pragma unroll
        for (int j = 0; j < 4; j++) {
            int col = col0 + wc * 64 + j * 16 + fr;
            if (col < 300) {
                float bias = b2[col];
                float wv   = W3[col];
#pragma unroll
                for (int r = 0; r < 4; r++)
                    p[r] += fmaxf(acc[i][j][r] + bias, 0.f) * wv;
            }
        }
#pragma unroll
        for (int r = 0; r < 4; r++) {
            float v = p[r];
            v += __shfl_xor(v, 1, 64);
            v += __shfl_xor(v, 2, 64);
            v += __shfl_xor(v, 4, 64);
            v += __shfl_xor(v, 8, 64);
            p[r] = v;
        }
        if (fr == 0) {
#pragma unroll
            for (int r = 0; r < 4; r++)
                atomicAdd(&sE[wr * 64 + i * 16 + fq * 4 + r], p[r]);
        }
    }
    __syncthreads();
    if (t < 128) {
        int row = row0 + t;
        if (row < N) atomicAdd(&energy[row], sE[t]);
    }
}

// ---------------------------------------------------------------------------
// K5: per-graph pool. batch sorted -> wave-segmented reduce, few atomics.
// ---------------------------------------------------------------------------
__global__ void k_pool(const float* __restrict__ energy, const int* __restrict__ batch,
                       float* __restrict__ dg, int N) {
    int i = blockIdx.x * blockDim.x + threadIdx.x;
    int lane = threadIdx.x & 63;
    float v = (i < N) ? energy[i] : 0.f;
    int   b = (i < N) ? batch[i]  : -1;
#pragma unroll
    for (int off = 1; off < 64; off <<= 1) {
        float vv = __shfl_down(v, off, 64);
        int   bb = __shfl_down(b, off, 64);
        if (lane + off < 64 && bb == b) v += vv;
    }
    int pb = __shfl_up(b, 1, 64);
    if (i < N && (lane == 0 || pb != b)) atomicAdd(&dg[b], v);
}

extern "C" void kernel_launch(void* const* d_in, const int* in_sizes, int n_in,
                              void* d_out, int out_size, void* d_ws, size_t ws_size,
                              hipStream_t stream) {
    const int* atom       = (const int*)d_in[0];
    const int* bond_index = (const int*)d_in[1];
    const int* bond_attr  = (const int*)d_in[2];
    const int* batch      = (const int*)d_in[3];
    const float* Wa   = (const float*)d_in[4];
    const float* Wh   = (const float*)d_in[5];
    const float* War  = (const float*)d_in[6];
    const float* Wc   = (const float*)d_in[7];
    const float* Wch  = (const float*)d_in[8];
    const float* Wbt  = (const float*)d_in[9];
    const float* Wbai = (const float*)d_in[10];
    const float* Wsla = (const float*)d_in[11];
    const float* Wsl  = (const float*)d_in[12];
    const float* W1   = (const float*)d_in[13];
    const float* b1   = (const float*)d_in[14];
    const float* W2   = (const float*)d_in[15];
    const float* b2   = (const float*)d_in[16];
    const float* W3   = (const float*)d_in[17];

    int N = in_sizes[0] / 5;    // 50000
    int E = in_sizes[1] / 2;    // 100000
    int rBT  = in_sizes[9]  / EMB;   // 22
    int rBAI = in_sizes[10] / EMB;   // 119
    int rSLA = in_sizes[11] / EMB;   // 119
    int NCOMBO = rBT * rBAI;         // 2618
    int Mb = (N + 127) / 128;   // 391
    int Npad = Mb * 128;        // 50048
    int nTiles = Npad / 16;     // 3128 row-blocks
    int nb = (N + 255) / 256;   // 196 scan blocks

    size_t regionBytes = (size_t)Npad * KP * 4;
    char* base = (char*)d_ws;
    ushortT* nodeAb = (ushortT*)base;                  // region0: embed out (bf16 rows)
    ushortT* nodeBh = (ushortT*)(base + regionBytes);  // region1: mp1 out (bf16 rows)
    short8* Af = (short8*)nodeAb;                      // region0 reuse: mp2 out frags
    short8* Hf = (short8*)nodeBh;                      // region1 reuse: gemm1 out frags
    char* tail = base + 2 * regionBytes;
    float* energy  = (float*)tail;
    int* counts    = (int*)(energy + N);
    int* offsets   = counts + N;
    int* cursor    = offsets + N;
    int* src_list  = cursor + N;
    int* cidx_list = src_list + E;
    short8* W1f    = (short8*)(cidx_list + E);         // 40*19*64 tiles
    short8* W2f    = W1f + 40 * 19 * 64;               // 24*19*64 tiles
    int* blocksums = (int*)(W2f + 24 * 19 * 64);
    int* blockpref = blocksums + 256;
    ushortT* Tcombo = (ushortT*)(blockpref + 256);     // 2618*600 bf16 = 3.1 MB
    ushortT* Tslc   = Tcombo + (size_t)NCOMBO * EMB;   // 119*600 bf16

    const int* bsrc = bond_index;
    const int* bdst = bond_index + E;

    // CSR build (dst -> edges), storing src+combo-index in CSR order
    hipMemsetAsync(counts, 0, (size_t)N * sizeof(int), stream);
    k_hist<<<(E + 255) / 256, 256, 0, stream>>>(bdst, counts, E);
    k_scan_l1<<<nb, 256, 0, stream>>>(counts, offsets, blocksums, N);
    k_scan_l2<<<1, 256, 0, stream>>>(blocksums, blockpref, nb);
    k_scan_l3<<<nb, 256, 0, stream>>>(offsets, cursor, blockpref, N);
    k_scatter2<<<(E + 255) / 256, 256, 0, stream>>>(bsrc, bdst, bond_attr, cursor,
                                                    src_list, cidx_list, E, rBAI);

    // combo / self-loop tables (bf16, fp32-summed)
    {
        int tot = NCOMBO * 75;
        k_combo<<<(tot + 255) / 256, 256, 0, stream>>>(Wbt, Wbai, Tcombo, rBAI, tot);
        tot = rSLA * 75;
        k_slc<<<(tot + 255) / 256, 256, 0, stream>>>(Wsla, Wsl, Tslc, tot);
    }

    // weight splits to fragment-interleaved single bf16
    k_split_w_frag<<<(40 * 19 * 64 + 255) / 256, 256, 0, stream>>>(W1, W1f, 600, 40);
    k_split_w_frag<<<(24 * 19 * 64 + 255) / 256, 256, 0, stream>>>(W2, W2f, 300, 24);

    // K1: node embedding -> nodeAb (bf16 rows)
    {
        int total = N * Q4;
        k_node_embed_b<<<(total + 255) / 256, 256, 0, stream>>>(
            atom, (const float4*)Wa, (const float4*)Wh, (const float4*)War,
            (const float4*)Wc, (const float4*)Wch, nodeAb, N);
    }

    int mpblocks = (2 * N * 64 + 255) / 256;   // two waves per node
    // round 1: nodeAb (bf16) -> nodeBh (bf16 rows)
    k_mp_gather_b<<<mpblocks, 256, 0, stream>>>(src_list, cidx_list, atom,
        offsets, counts, Tcombo, Tslc, nodeAb, nodeBh, N);

    // zero A-frag pad tiles (rows N..Npad; region0 embed data is dead now)
    {
        int firstPad = N / 16;
        size_t offB  = (size_t)firstPad * 1216 * 16;
        size_t cntB  = (size_t)(nTiles - firstPad) * 1216 * 16;
        if (cntB) hipMemsetAsync((char*)Af + offB, 0, cntB, stream);
    }

    // round 2 fused with relu + single-bf16 frag cast: nodeBh -> Af
    k_mp_gather_rs<<<mpblocks, 256, 0, stream>>>(src_list, cidx_list, atom,
        offsets, counts, Tcombo, Tslc, nodeBh, (ushortT*)Af, N);

    // GEMM1: Af x W1f -> Hf (region1; nodeBh dead)
    k_gemm1r<<<Mb * 5, 256, 0, stream>>>(Af, W1f, b1, (ushortT*)Hf, N);

    // GEMM2: Hf x W2f (+b2, W3) -> energy (atomic accumulate)
    hipMemsetAsync(energy, 0, (size_t)N * sizeof(float), stream);
    k_gemm2r<<<Mb * 3, 256, 0, stream>>>(Hf, W2f, b2, W3, energy, N);

    // pool
    hipMemsetAsync(d_out, 0, (size_t)out_size * sizeof(float), stream);
    k_pool<<<(N + 255) / 256, 256, 0, stream>>>(energy, batch, (float*)d_out, N);
}